// Round 7
// baseline (473.651 us; speedup 1.0000x reference)
//
#include <hip/hip_runtime.h>
#include <math.h>

#define T_STEPS 1024
#define BATCH   32
#define DIM     1024
#define NST     64
#define TBN     ((size_t)T_STEPS * BATCH * NST)   // 2M elements per projection
#define LOG2E   1.44269504088896340736f

typedef __attribute__((ext_vector_type(8))) short bf16x8;
typedef __attribute__((ext_vector_type(4))) float f32x4;

// ws layout (floats): k | v | q | a  (4 x TBN), then Whi/Wlo (bf16, 256x1024 each),
// then d2 (T*B floats).  Total ~34.8 MB.
#define WS_WSPLIT (4 * TBN)                    // float offset of Whi
#define WS_D2     (4 * TBN + 262144)           // float offset of d2 (Whi+Wlo = 1MB = 262144 floats)

// ======================= Kernel 0: split W into bf16 hi/lo =======================
__global__ __launch_bounds__(256)
void split_w(const float* __restrict__ Wk, const float* __restrict__ Wv,
             const float* __restrict__ Wq, const float* __restrict__ Wa,
             short* __restrict__ Whi, short* __restrict__ Wlo)
{
    const int idx = (blockIdx.x * 256 + threadIdx.x) * 4;   // 0..262140
    const int n   = idx >> 10;
    const int k   = idx & 1023;
    const float* W = (n < 64) ? Wk : (n < 128) ? Wv : (n < 192) ? Wq : Wa;
    float4 v = *(const float4*)(W + ((size_t)(n & 63) << 10) + k);
    float f[4] = {v.x, v.y, v.z, v.w};
    unsigned h[4], l[4];
    #pragma unroll
    for (int i = 0; i < 4; i++) {
        unsigned hb = __float_as_uint(f[i]) & 0xffff0000u;
        h[i] = hb >> 16;
        l[i] = __float_as_uint(f[i] - __uint_as_float(hb)) >> 16;
    }
    uint2 hp, lp;
    hp.x = h[0] | (h[1] << 16);  hp.y = h[2] | (h[3] << 16);
    lp.x = l[0] | (l[1] << 16);  lp.y = l[2] | (l[3] << 16);
    *(uint2*)(Whi + idx) = hp;
    *(uint2*)(Wlo + idx) = lp;
}

// ======================= Phase 1: MFMA GEMM (pre-split W) =======================
// Tile 64(M) x 256(N) x 32(K); 256 thr = 4 waves; wave w owns projection w's 64 cols.
// A: fp32->hi/lo converted in-kernel, staged in padded LDS (depth-2 reg prefetch).
// B: bf16 fragments loaded straight from global Whi/Wlo (L1/L2-resident), depth-1 prefetch.

__device__ __forceinline__ void cvt_hi_lo(const float4& v0, const float4& v1,
                                          uint4& hi, uint4& lo)
{
    float f[8] = {v0.x, v0.y, v0.z, v0.w, v1.x, v1.y, v1.z, v1.w};
    unsigned hb[8], lb[8];
    #pragma unroll
    for (int i = 0; i < 8; i++) {
        unsigned bits = __float_as_uint(f[i]);
        hb[i] = bits & 0xffff0000u;
        lb[i] = __float_as_uint(f[i] - __uint_as_float(hb[i]));
    }
    hi.x = (hb[0] >> 16) | hb[1];
    hi.y = (hb[2] >> 16) | hb[3];
    hi.z = (hb[4] >> 16) | hb[5];
    hi.w = (hb[6] >> 16) | hb[7];
    lo.x = (lb[0] >> 16) | (lb[1] & 0xffff0000u);
    lo.y = (lb[2] >> 16) | (lb[3] & 0xffff0000u);
    lo.z = (lb[4] >> 16) | (lb[5] & 0xffff0000u);
    lo.w = (lb[6] >> 16) | (lb[7] & 0xffff0000u);
}

__global__ __launch_bounds__(256, 2)
void proj_gemm_mfma(const float* __restrict__ x,
                    const short* __restrict__ Whi,
                    const short* __restrict__ Wlo,
                    float* __restrict__ ws)
{
    // pad to 40 shorts (80 B, 16B-aligned): fragment-read banks spread evenly
    __shared__ short Ahi[64][40], Alo[64][40];   // 10 KB total

    const int tid  = threadIdx.x;
    const int lane = tid & 63;
    const int wave = tid >> 6;
    const int m0   = blockIdx.x * 64;

    const int am = tid >> 2;            // staging row 0..63
    const int ak = (tid & 3) * 8;       // staging k-offset 0,8,16,24
    const float* agp = x + (size_t)(m0 + am) * DIM + ak;

    const int fr = lane & 15;
    const int fk = (lane >> 4) * 8;

    const short* bhp[4];
    const short* blp[4];
    #pragma unroll
    for (int nt = 0; nt < 4; nt++) {
        const int n = wave * 64 + nt * 16 + fr;
        bhp[nt] = Whi + (size_t)n * DIM + fk;
        blp[nt] = Wlo + (size_t)n * DIM + fk;
    }

    f32x4 acc[4][4];
    #pragma unroll
    for (int i = 0; i < 4; i++)
        #pragma unroll
        for (int j = 0; j < 4; j++)
            acc[i][j] = (f32x4)0.0f;

    // A depth-2 register prefetch
    float4 a0[2], a1[2];
    a0[0] = *(const float4*)(agp);       a1[0] = *(const float4*)(agp + 4);
    a0[1] = *(const float4*)(agp + 32);  a1[1] = *(const float4*)(agp + 36);

    // B depth-1 prefetch
    bf16x8 bh[4], bl[4];
    #pragma unroll
    for (int nt = 0; nt < 4; nt++) {
        bh[nt] = *(const bf16x8*)(bhp[nt]);
        bl[nt] = *(const bf16x8*)(blp[nt]);
    }

    #pragma unroll 1
    for (int kb = 0; kb < 32; kb++) {
        const int sl = kb & 1;
        {   // convert + write A tile for this K-block
            uint4 hi, lo;
            cvt_hi_lo(a0[sl], a1[sl], hi, lo);
            *(uint4*)&Ahi[am][ak] = hi;
            *(uint4*)&Alo[am][ak] = lo;
        }
        __syncthreads();                 // tile ready

        // refill A slot with kb+2 (covers ~2 iterations of latency)
        {
            const int kn = (kb + 2 < 32) ? (kb + 2) * 32 : kb * 32;
            a0[sl] = *(const float4*)(agp + kn);
            a1[sl] = *(const float4*)(agp + kn + 4);
        }

        // A fragments from LDS
        bf16x8 ah[4], al[4];
        #pragma unroll
        for (int mt = 0; mt < 4; mt++) {
            ah[mt] = *(const bf16x8*)&Ahi[mt * 16 + fr][fk];
            al[mt] = *(const bf16x8*)&Alo[mt * 16 + fr][fk];
        }

        // B fragments for kb+1 (global, L1/L2)
        bf16x8 nh[4], nl[4];
        {
            const int ko = ((kb + 1) & 31) * 32;
            #pragma unroll
            for (int nt = 0; nt < 4; nt++) {
                nh[nt] = *(const bf16x8*)(bhp[nt] + ko);
                nl[nt] = *(const bf16x8*)(blp[nt] + ko);
            }
        }

        #pragma unroll
        for (int mt = 0; mt < 4; mt++)
            #pragma unroll
            for (int nt = 0; nt < 4; nt++) {
                acc[mt][nt] = __builtin_amdgcn_mfma_f32_16x16x32_bf16(ah[mt], bh[nt], acc[mt][nt], 0, 0, 0);
                acc[mt][nt] = __builtin_amdgcn_mfma_f32_16x16x32_bf16(al[mt], bh[nt], acc[mt][nt], 0, 0, 0);
                acc[mt][nt] = __builtin_amdgcn_mfma_f32_16x16x32_bf16(ah[mt], bl[nt], acc[mt][nt], 0, 0, 0);
            }
        __syncthreads();                 // reads done before next write

        #pragma unroll
        for (int nt = 0; nt < 4; nt++) { bh[nt] = nh[nt]; bl[nt] = nl[nt]; }
    }

    // epilogue: C/D layout col = lane&15 (n), row = (lane>>4)*4 + reg (m)
    float* outb = ws + (size_t)wave * TBN;
    const int r0 = (lane >> 4) * 4;
    #pragma unroll
    for (int mt = 0; mt < 4; mt++)
        #pragma unroll
        for (int nt = 0; nt < 4; nt++)
            #pragma unroll
            for (int r = 0; r < 4; r++)
                outb[(size_t)(m0 + mt * 16 + r0 + r) * NST + nt * 16 + fr] = acc[mt][nt][r];
}

// ======================= Kernel 2: d2 = k_t . k_{t+1}, and fold a' = -(ax+ba)*log2e ====
template <int CTRL>
__device__ __forceinline__ float dpp_add(float v) {
    int o = __builtin_amdgcn_mov_dpp(__float_as_int(v), CTRL, 0xF, 0xF, true);
    return v + __int_as_float(o);
}
__device__ __forceinline__ float reduce16(float v) {
    v = dpp_add<0xB1>(v);     // quad_perm [1,0,3,2]
    v = dpp_add<0x4E>(v);     // quad_perm [2,3,0,1]
    v = dpp_add<0x141>(v);    // ROW_HALF_MIRROR
    v = dpp_add<0x140>(v);    // ROW_MIRROR
    return v;
}

__global__ __launch_bounds__(256)
void d2_prep(const float* __restrict__ kb_, float* __restrict__ ab_,
             const float* __restrict__ b_alpha, float* __restrict__ d2g)
{
    const size_t stp = (size_t)BATCH * NST;
    if (blockIdx.x < 2048) {
        // d2 part: block covers batch b, 16 t's (4 waves x 4)
        const int b    = blockIdx.x >> 6;
        const int tb   = (blockIdx.x & 63) * 16;
        const int lane = threadIdx.x & 63;
        const int wv   = threadIdx.x >> 6;
        const int s    = lane >> 4;
        const int cl   = lane & 15;
        const int t    = tb + wv * 4 + s;
        const int t1   = (t + 1 < T_STEPS) ? t + 1 : t;
        float4 k0 = *(const float4*)(kb_ + (size_t)t  * stp + b * NST + cl * 4);
        float4 k1 = *(const float4*)(kb_ + (size_t)t1 * stp + b * NST + cl * 4);
        float d = k0.x * k1.x;
        d = fmaf(k0.y, k1.y, d);
        d = fmaf(k0.z, k1.z, d);
        d = fmaf(k0.w, k1.w, d);
        d = reduce16(d);
        if (cl == 0) d2g[b * T_STEPS + t] = d;
    } else {
        // a-transform part: a' = -(a + ba) * log2e, in place (2M elements)
        const int blk = blockIdx.x - 2048;
        const size_t e = (size_t)blk * 1024 + threadIdx.x * 4;
        const int n0  = (threadIdx.x * 4) & 63;
        float4 ba = *(const float4*)(b_alpha + n0);
        float4 a  = *(const float4*)(ab_ + e);
        a.x = -(a.x + ba.x) * LOG2E;
        a.y = -(a.y + ba.y) * LOG2E;
        a.z = -(a.z + ba.z) * LOG2E;
        a.w = -(a.w + ba.w) * LOG2E;
        *(float4*)(ab_ + e) = a;
    }
}

// ======================= Phase 2: sequential scan =======================
// ret_{t+1} = a_t*(S_{t-1}.k_{t+1}) + (1-a_t)*v_t*d2_t ; d2 precomputed.
// 16 lanes/row, 4 rows/wave, 512 single-wave blocks. LDS dbuf 16-step chunks.
// Per-step LDS: knx(b128) + qf(b128) + vad(b128: v, a', d2).

__device__ __forceinline__ float fast_sigmoid_n(float zn) {   // zn = -z*log2e already
    float e = __builtin_amdgcn_exp2f(zn);
    return __builtin_amdgcn_rcpf(1.0f + e);
}

#define SCH 16
#define NCH (T_STEPS / SCH)

__global__ __launch_bounds__(64, 1)
void scan16_kernel(const float* __restrict__ ws,
                   const float* __restrict__ S0,
                   const float* __restrict__ d_alpha,
                   const float* __restrict__ d2g,
                   float* __restrict__ out)
{
    const float* kb_ = ws;
    const float* vb_ = ws + TBN;
    const float* qb_ = ws + 2 * TBN;
    const float* ab_ = ws + 3 * TBN;   // pre-transformed: -(ax+ba)*log2e

    __shared__ float kq[2][SCH][128];    // [0..63]=k_t, [64..127]=q_t
    __shared__ float vad[2][SCH][4][4];  // per row: (v, a', d2, 0)

    const int lane = threadIdx.x;
    const int b    = blockIdx.x >> 4;
    const int rg   = blockIdx.x & 15;
    const int rl   = lane >> 4;         // row within group
    const int cl   = lane & 15;
    const int row  = rg * 4 + rl;
    const int c0   = cl * 4;

    float S[4];
    {
        float4 sv = *(const float4*)(S0 + ((size_t)b * NST + row) * NST + c0);
        S[0] = sv.x; S[1] = sv.y; S[2] = sv.z; S[3] = sv.w;
    }
    const float da2 = -LOG2E * d_alpha[row];

    const size_t stp = (size_t)BATCH * NST;

    // kq staging: 512 float4/chunk, 8 per lane
    int kqs[8], kqf[8];
    const float* kqg[8];
    #pragma unroll
    for (int p = 0; p < 8; p++) {
        const int idx = p * 64 + lane;
        const int s   = idx >> 5;
        const int f   = idx & 31;
        kqs[p] = s; kqf[p] = f;
        kqg[p] = ((f < 16) ? kb_ : qb_) + (size_t)s * stp + (size_t)b * NST + (f & 15) * 4;
    }
    // vad staging: 64 float4/chunk = 1 per lane: s=lane>>2, r=lane&3
    const int vs = lane >> 2;
    const int vr = lane & 3;
    const float* vgv = vb_ + (size_t)vs * stp + (size_t)b * NST + rg * 4 + vr;
    const float* vga = ab_ + (size_t)vs * stp + (size_t)b * NST + rg * 4 + vr;
    const float* vgd = d2g + (size_t)b * T_STEPS + vs;

    auto issue = [&](int ch, float4 (&rk)[8], float& rv, float& ra, float& rd) {
        const size_t off = (size_t)ch * SCH * stp;
        #pragma unroll
        for (int p = 0; p < 8; p++)
            rk[p] = *(const float4*)(kqg[p] + off);
        rv = vgv[off];
        ra = vga[off];
        rd = vgd[(size_t)ch * SCH];
    };
    auto commit = [&](int bi, const float4 (&rk)[8], float rv, float ra, float rd) {
        #pragma unroll
        for (int p = 0; p < 8; p++)
            *(float4*)&kq[bi][kqs[p]][kqf[p] * 4] = rk[p];
        *(float4*)&vad[bi][vs][vr] = make_float4(rv, ra, rd, 0.f);
    };

    {   // prologue: chunks 0,1 resident
        float4 rk[8]; float rv, ra, rd;
        issue(0, rk, rv, ra, rd); commit(0, rk, rv, ra, rd);
        issue(1, rk, rv, ra, rd); commit(1, rk, rv, ra, rd);
    }

    float kcur[4];
    *(float4*)kcur = *(const float4*)&kq[0][0][c0];

    float ret;
    {
        float p0 = S[0] * kcur[0];
        p0 = fmaf(S[1], kcur[1], p0);
        p0 = fmaf(S[2], kcur[2], p0);
        p0 = fmaf(S[3], kcur[3], p0);
        ret = reduce16(p0);
    }

    float* op = out + (size_t)b * NST + row;

    for (int ch = 0; ch < NCH; ch++) {
        const int cur = ch & 1, nxt = cur ^ 1;

        float4 rk[8]; float rv, ra, rd;
        const int cn = (ch + 2 < NCH) ? ch + 2 : NCH - 1;
        issue(cn, rk, rv, ra, rd);   // loads fly under the 16-step compute

        #pragma unroll
        for (int s = 0; s < SCH; s++) {
            const int t = ch * SCH + s;
            float qf[4], knx[4];
            *(float4*)qf = *(const float4*)&kq[cur][s][64 + c0];
            if (s < SCH - 1) *(float4*)knx = *(const float4*)&kq[cur][s + 1][c0];
            else             *(float4*)knx = *(const float4*)&kq[nxt][0][c0];
            const float4 vv4 = *(const float4*)&vad[cur][s][rl];   // (v, a', d2)

            // chain: fma -> exp2 -> add -> rcp
            const float zn    = fmaf(da2, ret, vv4.y);
            const float alpha = fast_sigmoid_n(zn);

            // shadow dot (old S, next k)
            float d1 = S[0] * knx[0];
            d1 = fmaf(S[1], knx[1], d1);
            d1 = fmaf(S[2], knx[2], d1);
            d1 = fmaf(S[3], knx[3], d1);
            d1 = reduce16(d1);

            const float w = (1.f - alpha) * vv4.x;
            S[0] = fmaf(alpha, S[0], w * kcur[0]);
            S[1] = fmaf(alpha, S[1], w * kcur[1]);
            S[2] = fmaf(alpha, S[2], w * kcur[2]);
            S[3] = fmaf(alpha, S[3], w * kcur[3]);

            const float c2v = vv4.x * vv4.z;
            ret = fmaf(alpha, d1 - c2v, c2v);

            float h = S[0] * qf[0];
            h = fmaf(S[1], qf[1], h);
            h = fmaf(S[2], qf[2], h);
            h = fmaf(S[3], qf[3], h);
            h = reduce16(h);
            const float o = h * h * fast_sigmoid_n(-h * LOG2E);   // h * silu(h)
            if (cl == 0) op[(size_t)t * stp] = o;

            kcur[0] = knx[0]; kcur[1] = knx[1];
            kcur[2] = knx[2]; kcur[3] = knx[3];
        }

        commit(cur, rk, rv, ra, rd);
    }

    float* sfp = out + TBN + ((size_t)b * NST + row) * NST + c0;
    *(float4*)sfp = make_float4(S[0], S[1], S[2], S[3]);
}

// ======================= launch =======================

extern "C" void kernel_launch(void* const* d_in, const int* in_sizes, int n_in,
                              void* d_out, int out_size, void* d_ws, size_t ws_size,
                              hipStream_t stream)
{
    const float* x  = (const float*)d_in[0];
    const float* S0 = (const float*)d_in[1];
    const float* Wk = (const float*)d_in[2];
    const float* Wv = (const float*)d_in[3];
    const float* Wq = (const float*)d_in[4];
    const float* Wa = (const float*)d_in[5];
    const float* da = (const float*)d_in[6];
    const float* ba = (const float*)d_in[7];
    float* out = (float*)d_out;
    float* ws  = (float*)d_ws;

    short* Whi = (short*)(ws + WS_WSPLIT);
    short* Wlo = Whi + 256 * 1024;
    float* d2g = ws + WS_D2;

    split_w<<<dim3(256), 256, 0, stream>>>(Wk, Wv, Wq, Wa, Whi, Wlo);

    proj_gemm_mfma<<<dim3((T_STEPS * BATCH) / 64), 256, 0, stream>>>(x, Whi, Wlo, ws);

    d2_prep<<<dim3(4096), 256, 0, stream>>>(ws, ws + 3 * TBN, ba, d2g);

    scan16_kernel<<<dim3(BATCH * 16), 64, 0, stream>>>(ws, S0, da, d2g, out);
}